// Round 2
// baseline (626.710 us; speedup 1.0000x reference)
//
#include <hip/hip_runtime.h>
#include <hip/hip_bf16.h>
#include <math.h>

// Problem constants
#define Bb 2
#define Hh 128
#define Wd 128
#define Cc 96
#define Dd 192
#define Ll 16384        // Hh*Wd
#define Nn 16
#define Rr 6
#define DL 3145728      // Dd*Ll
#define NCHUNK 512
#define CLEN 32
#define CSHIFT 9        // log2(NCHUNK)
#define NSG 32          // supergroups per chain (16 chunks each)

__device__ __forceinline__ float siluf(float v) { return v / (1.f + __expf(-v)); }
__device__ __forceinline__ float geluf(float v) { return 0.5f * v * (1.f + erff(v * 0.70710678118654752f)); }
__device__ __forceinline__ float softplusf(float v) {
    float a = fabsf(v);
    return fmaxf(v, 0.f) + log1pf(__expf(-a));
}

// ---------------------------------------------------------------------------
// K2: GEMM with K=96.  A (M x 96) pos-major, W (Nout x 96) row-major.
// MODE 0: A = x, LN fused; o<192 -> xi (B,D,L), o>=192 -> z pos-major.
// MODE 1: A = high_branch_low (no LN); all outputs -> (B,D,L).
// ---------------------------------------------------------------------------
template <int MODE>
__global__ __launch_bounds__(256) void gemm96_k(
    const float* __restrict__ A, const float* __restrict__ W,
    float* __restrict__ outA, float* __restrict__ outB,
    const float* __restrict__ lng, const float* __restrict__ lnb)
{
    __shared__ float sA[96 * 68];   // [k][row], padded row stride 68
    __shared__ float sW[96 * 68];
    __shared__ float redS[512];
    __shared__ float meanS[64], rstdS[64];

    const int t = threadIdx.x;
    const int m0 = blockIdx.x * 64;
    const int n0 = blockIdx.y * 64;

    #pragma unroll
    for (int i = 0; i < 6; ++i) {
        int idx = t + i * 256;          // float4 index, 0..1535
        int row = idx / 24, c4 = idx % 24;
        float4 v = *reinterpret_cast<const float4*>(A + (size_t)(m0 + row) * 96 + c4 * 4);
        int c = c4 * 4;
        sA[(c + 0) * 68 + row] = v.x; sA[(c + 1) * 68 + row] = v.y;
        sA[(c + 2) * 68 + row] = v.z; sA[(c + 3) * 68 + row] = v.w;
    }
    #pragma unroll
    for (int i = 0; i < 6; ++i) {
        int idx = t + i * 256;
        int row = idx / 24, c4 = idx % 24;
        float4 v = *reinterpret_cast<const float4*>(W + (size_t)(n0 + row) * 96 + c4 * 4);
        int c = c4 * 4;
        sW[(c + 0) * 68 + row] = v.x; sW[(c + 1) * 68 + row] = v.y;
        sW[(c + 2) * 68 + row] = v.z; sW[(c + 3) * 68 + row] = v.w;
    }
    __syncthreads();

    if (MODE == 0) {
        int r = t & 63, part = t >> 6;          // 4 parts x 24 channels
        float s = 0.f, s2 = 0.f;
        for (int k = part * 24; k < part * 24 + 24; ++k) {
            float v = sA[k * 68 + r]; s += v; s2 += v * v;
        }
        redS[part * 64 + r] = s; redS[256 + part * 64 + r] = s2;
        __syncthreads();
        if (t < 64) {
            float ts = 0.f, ts2 = 0.f;
            #pragma unroll
            for (int p = 0; p < 4; ++p) { ts += redS[p * 64 + t]; ts2 += redS[256 + p * 64 + t]; }
            float mean = ts * (1.f / 96.f);
            float var = ts2 * (1.f / 96.f) - mean * mean;
            meanS[t] = mean; rstdS[t] = rsqrtf(var + 1e-5f);
        }
        __syncthreads();
        for (int k = part * 24; k < part * 24 + 24; ++k) {
            float v = sA[k * 68 + r];
            sA[k * 68 + r] = (v - meanS[r]) * rstdS[r] * lng[k] + lnb[k];
        }
        __syncthreads();
    }

    const int tc = t & 15, tr = t >> 4;
    float acc[4][4];
    #pragma unroll
    for (int q = 0; q < 4; ++q)
        #pragma unroll
        for (int j = 0; j < 4; ++j) acc[q][j] = 0.f;

    #pragma unroll 4
    for (int k = 0; k < 96; ++k) {
        float4 a4 = *reinterpret_cast<const float4*>(&sA[k * 68 + tr * 4]);
        float4 w4 = *reinterpret_cast<const float4*>(&sW[k * 68 + tc * 4]);
        acc[0][0] += a4.x * w4.x; acc[0][1] += a4.x * w4.y; acc[0][2] += a4.x * w4.z; acc[0][3] += a4.x * w4.w;
        acc[1][0] += a4.y * w4.x; acc[1][1] += a4.y * w4.y; acc[1][2] += a4.y * w4.z; acc[1][3] += a4.y * w4.w;
        acc[2][0] += a4.z * w4.x; acc[2][1] += a4.z * w4.y; acc[2][2] += a4.z * w4.z; acc[2][3] += a4.z * w4.w;
        acc[3][0] += a4.w * w4.x; acc[3][1] += a4.w * w4.y; acc[3][2] += a4.w * w4.z; acc[3][3] += a4.w * w4.w;
    }

    #pragma unroll
    for (int q = 0; q < 4; ++q) {
        int m = m0 + tr * 4 + q;
        int b = m >> 14, l = m & 16383;
        #pragma unroll
        for (int j = 0; j < 4; ++j) {
            int o = n0 + tc * 4 + j;
            float v = acc[q][j];
            if (MODE == 0) {
                if (o < Dd) outA[(size_t)b * DL + (size_t)o * Ll + l] = v;
                else        outB[(size_t)m * Dd + (o - Dd)] = v;
            } else {
                outA[(size_t)b * DL + (size_t)o * Ll + l] = v;
            }
        }
    }
}

// ---------------------------------------------------------------------------
// K3: depthwise 3x3 conv, pad 1, + bias + SiLU.  (B,D,H,W) channel-major.
// ---------------------------------------------------------------------------
__global__ __launch_bounds__(128) void conv3x3_k(
    const float* __restrict__ xin, const float* __restrict__ cw,
    const float* __restrict__ cb, float* __restrict__ xout)
{
    int w = threadIdx.x;      // 0..127
    int h = blockIdx.x;       // 0..127
    int d = blockIdx.y;       // 0..191
    int b = blockIdx.z;
    const float* base = xin + (size_t)(b * Dd + d) * Ll;
    float wgt[9];
    #pragma unroll
    for (int i = 0; i < 9; ++i) wgt[i] = cw[d * 9 + i];
    float acc = cb[d];
    #pragma unroll
    for (int ky = 0; ky < 3; ++ky) {
        int hh = h + ky - 1;
        if (hh < 0 || hh >= Hh) continue;
        #pragma unroll
        for (int kx = 0; kx < 3; ++kx) {
            int ww = w + kx - 1;
            if (ww < 0 || ww >= Wd) continue;
            acc += wgt[ky * 3 + kx] * base[hh * Wd + ww];
        }
    }
    xout[(size_t)(b * Dd + d) * Ll + h * Wd + w] = siluf(acc);
}

// ---------------------------------------------------------------------------
// K4a: low_dbl rows 6..37 + SimpleGate for B and C.  One thread per position.
// ---------------------------------------------------------------------------
__global__ __launch_bounds__(256) void lowdbl_gates_k(
    const float* __restrict__ low, const float* __restrict__ wl,
    const float* __restrict__ b1, const float* __restrict__ b2,
    const float* __restrict__ c1, const float* __restrict__ c2,
    float* __restrict__ bs_low, float* __restrict__ cs_low)
{
    __shared__ float wt[192 * 32];    // wt[d*32+c] = wl[(6+c)*192+d]
    __shared__ float w1b[192 * 16];
    __shared__ float w2bt[96 * 16];   // w2bt[j*16+c] = b2[c*96+j]
    __shared__ float w1c[192 * 16];
    __shared__ float w2ct[96 * 16];
    int t = threadIdx.x;
    for (int i = t; i < 32 * 192; i += 256) {
        int r = i / 192, dcol = i % 192;
        wt[dcol * 32 + r] = wl[(6 + r) * 192 + dcol];
    }
    for (int i = t; i < 3072; i += 256) { w1b[i] = b1[i]; w1c[i] = c1[i]; }
    for (int i = t; i < 1536; i += 256) {
        int c = i / 96, j = i % 96;
        w2bt[j * 16 + c] = b2[i]; w2ct[j * 16 + c] = c2[i];
    }
    __syncthreads();

    int pos = blockIdx.x * 256 + t;
    int b = pos >> 14, l = pos & 16383;
    const float* lp = low + (size_t)b * DL + l;

    float Bin[16], Cin[16];
    #pragma unroll
    for (int q = 0; q < 16; ++q) { Bin[q] = 0.f; Cin[q] = 0.f; }
    for (int d = 0; d < 192; ++d) {
        float v = lp[(size_t)d * Ll];
        const float4* w4p = reinterpret_cast<const float4*>(&wt[d * 32]);
        #pragma unroll
        for (int q = 0; q < 4; ++q) {
            float4 f = w4p[q];
            Bin[4 * q + 0] += v * f.x; Bin[4 * q + 1] += v * f.y;
            Bin[4 * q + 2] += v * f.z; Bin[4 * q + 3] += v * f.w;
        }
        #pragma unroll
        for (int q = 0; q < 4; ++q) {
            float4 f = w4p[4 + q];
            Cin[4 * q + 0] += v * f.x; Cin[4 * q + 1] += v * f.y;
            Cin[4 * q + 2] += v * f.z; Cin[4 * q + 3] += v * f.w;
        }
    }

    float Bout[16], Cout[16];
    #pragma unroll
    for (int q = 0; q < 16; ++q) { Bout[q] = 0.f; Cout[q] = 0.f; }
    for (int j = 0; j < 96; ++j) {
        float h1 = 0.f, h2 = 0.f, g1 = 0.f, g2 = 0.f;
        #pragma unroll
        for (int q = 0; q < 4; ++q) {
            float4 a = reinterpret_cast<const float4*>(&w1b[j * 16])[q];
            float4 cvec = reinterpret_cast<const float4*>(&w1b[(j + 96) * 16])[q];
            h1 += a.x * Bin[4 * q] + a.y * Bin[4 * q + 1] + a.z * Bin[4 * q + 2] + a.w * Bin[4 * q + 3];
            h2 += cvec.x * Bin[4 * q] + cvec.y * Bin[4 * q + 1] + cvec.z * Bin[4 * q + 2] + cvec.w * Bin[4 * q + 3];
            float4 ac = reinterpret_cast<const float4*>(&w1c[j * 16])[q];
            float4 cc = reinterpret_cast<const float4*>(&w1c[(j + 96) * 16])[q];
            g1 += ac.x * Cin[4 * q] + ac.y * Cin[4 * q + 1] + ac.z * Cin[4 * q + 2] + ac.w * Cin[4 * q + 3];
            g2 += cc.x * Cin[4 * q] + cc.y * Cin[4 * q + 1] + cc.z * Cin[4 * q + 2] + cc.w * Cin[4 * q + 3];
        }
        float gB = geluf(h1) * h2;
        float gC = geluf(g1) * g2;
        #pragma unroll
        for (int q = 0; q < 4; ++q) {
            float4 f = reinterpret_cast<const float4*>(&w2bt[j * 16])[q];
            Bout[4 * q + 0] += f.x * gB; Bout[4 * q + 1] += f.y * gB;
            Bout[4 * q + 2] += f.z * gB; Bout[4 * q + 3] += f.w * gB;
            float4 fc = reinterpret_cast<const float4*>(&w2ct[j * 16])[q];
            Cout[4 * q + 0] += fc.x * gC; Cout[4 * q + 1] += fc.y * gC;
            Cout[4 * q + 2] += fc.z * gC; Cout[4 * q + 3] += fc.w * gC;
        }
    }
    #pragma unroll
    for (int c = 0; c < 16; ++c) {
        bs_low[(size_t)b * 16 * Ll + (size_t)c * Ll + l] = Bout[c];
        cs_low[(size_t)b * 16 * Ll + (size_t)c * Ll + l] = Cout[c];
    }
}

// ---------------------------------------------------------------------------
// K4b: x_dbl (rows 0..37), writes dts_raw and Bs+Bs_low / Cs+Cs_low.
// ---------------------------------------------------------------------------
__global__ __launch_bounds__(256) void xdbl_k(
    const float* __restrict__ xs, const float* __restrict__ xw,
    const float* __restrict__ bs_low, const float* __restrict__ cs_low,
    float* __restrict__ dts_raw, float* __restrict__ bs_sum, float* __restrict__ cs_sum)
{
    __shared__ float wdt[192 * 6];
    __shared__ float wB[192 * 16];
    __shared__ float wC[192 * 16];
    int t = threadIdx.x;
    for (int i = t; i < 38 * 192; i += 256) {
        int r = i / 192, dcol = i % 192;
        float v = xw[i];
        if (r < 6)       wdt[dcol * 6 + r] = v;
        else if (r < 22) wB[dcol * 16 + (r - 6)] = v;
        else             wC[dcol * 16 + (r - 22)] = v;
    }
    __syncthreads();

    int pos = blockIdx.x * 256 + t;
    int b = pos >> 14, l = pos & 16383;
    const float* xp = xs + (size_t)b * DL + l;

    float da[6], Ba[16], Ca[16];
    #pragma unroll
    for (int q = 0; q < 6; ++q) da[q] = 0.f;
    #pragma unroll
    for (int q = 0; q < 16; ++q) { Ba[q] = 0.f; Ca[q] = 0.f; }

    for (int d = 0; d < 192; ++d) {
        float v = xp[(size_t)d * Ll];
        #pragma unroll
        for (int q = 0; q < 3; ++q) {
            float2 f = reinterpret_cast<const float2*>(&wdt[d * 6])[q];
            da[2 * q] += v * f.x; da[2 * q + 1] += v * f.y;
        }
        #pragma unroll
        for (int q = 0; q < 4; ++q) {
            float4 f = reinterpret_cast<const float4*>(&wB[d * 16])[q];
            Ba[4 * q + 0] += v * f.x; Ba[4 * q + 1] += v * f.y;
            Ba[4 * q + 2] += v * f.z; Ba[4 * q + 3] += v * f.w;
        }
        #pragma unroll
        for (int q = 0; q < 4; ++q) {
            float4 f = reinterpret_cast<const float4*>(&wC[d * 16])[q];
            Ca[4 * q + 0] += v * f.x; Ca[4 * q + 1] += v * f.y;
            Ca[4 * q + 2] += v * f.z; Ca[4 * q + 3] += v * f.w;
        }
    }
    #pragma unroll
    for (int r = 0; r < 6; ++r)
        dts_raw[(size_t)b * 6 * Ll + (size_t)r * Ll + l] = da[r];
    #pragma unroll
    for (int c = 0; c < 16; ++c) {
        size_t o = (size_t)b * 16 * Ll + (size_t)c * Ll + l;
        bs_sum[o] = Ba[c] + bs_low[o];
        cs_sum[o] = Ca[c] + cs_low[o];
    }
}

// ---------------------------------------------------------------------------
// K5: depthwise 1-D conv, k=7, dilation 2, pad 6 (same length).
// TRANS=1 writes (B,L,CH) transposed.
// ---------------------------------------------------------------------------
template <int CH, int TRANS>
__global__ __launch_bounds__(256) void conv1d_k(
    const float* __restrict__ in, const float* __restrict__ w, float* __restrict__ out)
{
    int idx = blockIdx.x * 256 + threadIdx.x;   // over B*CH*L
    int l = idx & 16383;
    int bc = idx >> 14;
    int ch = bc % CH;
    int b = bc / CH;
    const float* ip = in + (size_t)bc * Ll;
    float acc = 0.f;
    #pragma unroll
    for (int k = 0; k < 7; ++k) {
        int li = l + 2 * k - 6;
        if (li >= 0 && li < Ll) acc += w[ch * 7 + k] * ip[li];
    }
    if (TRANS) out[((size_t)b * Ll + l) * CH + ch] = acc;
    else       out[(size_t)bc * Ll + l] = acc;
}

// ---------------------------------------------------------------------------
// K7: chunked selective scan, 16 states per THREAD, fused dt_proj+softplus.
// Task = (b,d,chunk), NCHUNK=512 chunks of CLEN=32.
// ---------------------------------------------------------------------------
__global__ __launch_bounds__(256) void scan_p1_k(
    const float* __restrict__ dts_c, const float* __restrict__ dw,
    const float* __restrict__ dpb_, const float* __restrict__ xs,
    const float* __restrict__ bs_c, const float* __restrict__ A_logs,
    float* __restrict__ S_buf, float* __restrict__ hend)
{
    int task = blockIdx.x * 256 + threadIdx.x;   // 196608 tasks
    int chunk = task & (NCHUNK - 1);
    int bd = task >> CSHIFT;
    int d = bd % Dd, b = bd / Dd;

    float Av[16];
    #pragma unroll
    for (int n = 0; n < 16; ++n) Av[n] = -__expf(A_logs[d * 16 + n]);
    float dwv[6];
    #pragma unroll
    for (int r = 0; r < 6; ++r) dwv[r] = dw[d * 6 + r];
    float dpb = dpb_[d];

    const float* up = xs + (size_t)bd * Ll + chunk * CLEN;
    const float* tp = dts_c + (size_t)b * 6 * Ll + chunk * CLEN;
    const float* bp = bs_c + ((size_t)b * Ll + (size_t)chunk * CLEN) * 16;

    float h[16];
    #pragma unroll
    for (int n = 0; n < 16; ++n) h[n] = 0.f;
    float S = 0.f;

    for (int t4 = 0; t4 < CLEN / 4; ++t4) {
        float4 u4 = *reinterpret_cast<const float4*>(up + t4 * 4);
        float ua[4] = {u4.x, u4.y, u4.z, u4.w};
        float ta[6][4];
        #pragma unroll
        for (int r = 0; r < 6; ++r) {
            float4 v = *reinterpret_cast<const float4*>(tp + (size_t)r * Ll + t4 * 4);
            ta[r][0] = v.x; ta[r][1] = v.y; ta[r][2] = v.z; ta[r][3] = v.w;
        }
        #pragma unroll
        for (int s = 0; s < 4; ++s) {
            int tt = t4 * 4 + s;
            float acc = dpb;
            #pragma unroll
            for (int r = 0; r < 6; ++r) acc += dwv[r] * ta[r][s];
            float dlt = softplusf(acc);
            S += dlt;
            float du = dlt * ua[s];
            const float4* brow = reinterpret_cast<const float4*>(bp + tt * 16);
            float4 B0 = brow[0], B1 = brow[1], B2 = brow[2], B3 = brow[3];
            float Bv[16] = {B0.x, B0.y, B0.z, B0.w, B1.x, B1.y, B1.z, B1.w,
                            B2.x, B2.y, B2.z, B2.w, B3.x, B3.y, B3.z, B3.w};
            #pragma unroll
            for (int n = 0; n < 16; ++n)
                h[n] = __expf(dlt * Av[n]) * h[n] + du * Bv[n];
        }
    }
    float4* hp = reinterpret_cast<float4*>(hend + (size_t)task * 16);
    hp[0] = make_float4(h[0], h[1], h[2], h[3]);
    hp[1] = make_float4(h[4], h[5], h[6], h[7]);
    hp[2] = make_float4(h[8], h[9], h[10], h[11]);
    hp[3] = make_float4(h[12], h[13], h[14], h[15]);
    S_buf[task] = S;
}

// p2a: per (bd, sg, n) serial over the 16 chunks of a supergroup.
// Converts hend -> local hin prefix (in place), S_buf -> local prefix sum
// (in place), emits per-supergroup aggregates.
__global__ __launch_bounds__(256) void scan_p2a_k(
    const float* __restrict__ A_logs, float* __restrict__ S_buf,
    float* __restrict__ hend, float* __restrict__ hend_sg,
    float* __restrict__ sumS_sg)
{
    int tid = blockIdx.x * 256 + threadIdx.x;   // 196608
    int n = tid & 15;
    int sg = (tid >> 4) & (NSG - 1);
    int bd = tid >> CSHIFT;
    int d = bd % Dd;
    float An = -__expf(A_logs[d * 16 + n]);
    float h = 0.f, prefS = 0.f;
    int task0 = bd * NCHUNK + sg * 16;
    for (int c = 0; c < 16; ++c) {
        int task = task0 + c;
        float Sv = S_buf[task];
        float he = hend[(size_t)task * 16 + n];
        hend[(size_t)task * 16 + n] = h;        // local hin
        if (n == 0) S_buf[task] = prefS;        // local prefix-S
        h = __expf(An * Sv) * h + he;
        prefS += Sv;
    }
    int idx = bd * NSG + sg;
    hend_sg[(size_t)idx * 16 + n] = h;
    if (n == 0) sumS_sg[idx] = prefS;
}

// p2b: per (bd, n) serial over the 32 supergroups.
__global__ __launch_bounds__(256) void scan_p2b_k(
    const float* __restrict__ A_logs, const float* __restrict__ sumS_sg,
    const float* __restrict__ hend_sg, float* __restrict__ hsg_in)
{
    int tid = blockIdx.x * 256 + threadIdx.x;   // 6144
    int n = tid & 15;
    int bd = tid >> 4;
    int d = bd % Dd;
    float An = -__expf(A_logs[d * 16 + n]);
    float h = 0.f;
    for (int sg = 0; sg < NSG; ++sg) {
        int idx = bd * NSG + sg;
        hsg_in[(size_t)idx * 16 + n] = h;
        h = __expf(An * sumS_sg[idx]) * h + hend_sg[(size_t)idx * 16 + n];
    }
}

// p3: recompute with carry; init h from supergroup carry + local prefix.
__global__ __launch_bounds__(256) void scan_p3_k(
    const float* __restrict__ dts_c, const float* __restrict__ dw,
    const float* __restrict__ dpb_, const float* __restrict__ xs,
    const float* __restrict__ bs_c, const float* __restrict__ cs_c,
    const float* __restrict__ S_buf, const float* __restrict__ hend,
    const float* __restrict__ hsg_in, const float* __restrict__ A_logs,
    const float* __restrict__ Ds, float* __restrict__ y)
{
    int task = blockIdx.x * 256 + threadIdx.x;
    int chunk = task & (NCHUNK - 1);
    int bd = task >> CSHIFT;
    int d = bd % Dd, b = bd / Dd;
    int sg = chunk >> 4;

    float Av[16];
    #pragma unroll
    for (int n = 0; n < 16; ++n) Av[n] = -__expf(A_logs[d * 16 + n]);
    float dwv[6];
    #pragma unroll
    for (int r = 0; r < 6; ++r) dwv[r] = dw[d * 6 + r];
    float dpb = dpb_[d];
    float Dsd = Ds[d];

    // initial state: carry into this chunk
    float prefS = S_buf[task];
    const float* hsgp = hsg_in + ((size_t)(bd * NSG + sg)) * 16;
    const float* hlp = hend + (size_t)task * 16;
    float h[16];
    #pragma unroll
    for (int n = 0; n < 16; ++n)
        h[n] = __expf(Av[n] * prefS) * hsgp[n] + hlp[n];

    const float* up = xs + (size_t)bd * Ll + chunk * CLEN;
    const float* tp = dts_c + (size_t)b * 6 * Ll + chunk * CLEN;
    const float* bp = bs_c + ((size_t)b * Ll + (size_t)chunk * CLEN) * 16;
    const float* cp = cs_c + ((size_t)b * Ll + (size_t)chunk * CLEN) * 16;
    float* yp = y + (size_t)bd * Ll + chunk * CLEN;

    for (int t4 = 0; t4 < CLEN / 4; ++t4) {
        float4 u4 = *reinterpret_cast<const float4*>(up + t4 * 4);
        float ua[4] = {u4.x, u4.y, u4.z, u4.w};
        float ta[6][4];
        #pragma unroll
        for (int r = 0; r < 6; ++r) {
            float4 v = *reinterpret_cast<const float4*>(tp + (size_t)r * Ll + t4 * 4);
            ta[r][0] = v.x; ta[r][1] = v.y; ta[r][2] = v.z; ta[r][3] = v.w;
        }
        float ya[4];
        #pragma unroll
        for (int s = 0; s < 4; ++s) {
            int tt = t4 * 4 + s;
            float acc = dpb;
            #pragma unroll
            for (int r = 0; r < 6; ++r) acc += dwv[r] * ta[r][s];
            float dlt = softplusf(acc);
            float du = dlt * ua[s];
            const float4* brow = reinterpret_cast<const float4*>(bp + tt * 16);
            float4 B0 = brow[0], B1 = brow[1], B2 = brow[2], B3 = brow[3];
            float Bv[16] = {B0.x, B0.y, B0.z, B0.w, B1.x, B1.y, B1.z, B1.w,
                            B2.x, B2.y, B2.z, B2.w, B3.x, B3.y, B3.z, B3.w};
            const float4* crow = reinterpret_cast<const float4*>(cp + tt * 16);
            float4 C0 = crow[0], C1 = crow[1], C2 = crow[2], C3 = crow[3];
            float Cv[16] = {C0.x, C0.y, C0.z, C0.w, C1.x, C1.y, C1.z, C1.w,
                            C2.x, C2.y, C2.z, C2.w, C3.x, C3.y, C3.z, C3.w};
            float yv = Dsd * ua[s];
            #pragma unroll
            for (int n = 0; n < 16; ++n) {
                h[n] = __expf(dlt * Av[n]) * h[n] + du * Bv[n];
                yv += h[n] * Cv[n];
            }
            ya[s] = yv;
        }
        *reinterpret_cast<float4*>(yp + t4 * 4) = make_float4(ya[0], ya[1], ya[2], ya[3]);
    }
}

// ---------------------------------------------------------------------------
// K8: out-LayerNorm over D=192 + silu(z) gating.  Tile of 32 positions.
// ---------------------------------------------------------------------------
__global__ __launch_bounds__(256) void outln_k(
    const float* __restrict__ y, const float* __restrict__ z,
    const float* __restrict__ og, const float* __restrict__ ob,
    float* __restrict__ gated)
{
    __shared__ float ly[192 * 32];
    __shared__ float redS[512];
    __shared__ float meanS[32], rstdS[32];
    int t = threadIdx.x;
    int pos0 = blockIdx.x * 32;
    int b = pos0 >> 14, l0 = pos0 & 16383;
    const float* yb = y + (size_t)b * DL + l0;
    #pragma unroll
    for (int i = 0; i < 6; ++i) {
        int f4i = t + i * 256;          // 0..1535
        int dch = f4i >> 3, lq = f4i & 7;
        float4 v = *reinterpret_cast<const float4*>(yb + (size_t)dch * Ll + lq * 4);
        *reinterpret_cast<float4*>(&ly[dch * 32 + lq * 4]) = v;
    }
    __syncthreads();
    int p = t & 31, part = t >> 5;      // 8 parts x 24 channels
    float s = 0.f, s2 = 0.f;
    for (int dch = part * 24; dch < part * 24 + 24; ++dch) {
        float v = ly[dch * 32 + p]; s += v; s2 += v * v;
    }
    redS[part * 32 + p] = s; redS[256 + part * 32 + p] = s2;
    __syncthreads();
    if (t < 32) {
        float ts = 0.f, ts2 = 0.f;
        #pragma unroll
        for (int q = 0; q < 8; ++q) { ts += redS[q * 32 + t]; ts2 += redS[256 + q * 32 + t]; }
        float mean = ts * (1.f / 192.f);
        float var = ts2 * (1.f / 192.f) - mean * mean;
        meanS[t] = mean; rstdS[t] = rsqrtf(var + 1e-5f);
    }
    __syncthreads();
    float mean = meanS[p], rstd = rstdS[p];
    size_t gbase = ((size_t)pos0 + p) * Dd;
    #pragma unroll
    for (int i = 0; i < 6; ++i) {
        int dch = part * 24 + i * 4;
        float4 zv = *reinterpret_cast<const float4*>(z + gbase + dch);
        float4 r;
        r.x = ((ly[(dch + 0) * 32 + p] - mean) * rstd * og[dch + 0] + ob[dch + 0]) * siluf(zv.x);
        r.y = ((ly[(dch + 1) * 32 + p] - mean) * rstd * og[dch + 1] + ob[dch + 1]) * siluf(zv.y);
        r.z = ((ly[(dch + 2) * 32 + p] - mean) * rstd * og[dch + 2] + ob[dch + 2]) * siluf(zv.z);
        r.w = ((ly[(dch + 3) * 32 + p] - mean) * rstd * og[dch + 3] + ob[dch + 3]) * siluf(zv.w);
        *reinterpret_cast<float4*>(gated + gbase + dch) = r;
    }
}

// ---------------------------------------------------------------------------
// K9: out_proj GEMM (M=32768, K=192, N=96) + residual x.
// ---------------------------------------------------------------------------
__global__ __launch_bounds__(256) void outproj_k(
    const float* __restrict__ g, const float* __restrict__ W,
    const float* __restrict__ x, float* __restrict__ out)
{
    __shared__ float la[48 * 68];     // [k][row]
    __shared__ float lw[48 * 97];     // [k][c] padded
    int t = threadIdx.x;
    int m0 = blockIdx.x * 64;
    int tc = t & 15, tr = t >> 4;
    float acc[4][6];
    #pragma unroll
    for (int q = 0; q < 4; ++q)
        #pragma unroll
        for (int j = 0; j < 6; ++j) acc[q][j] = 0.f;

    for (int k0 = 0; k0 < 192; k0 += 48) {
        __syncthreads();
        #pragma unroll
        for (int i = 0; i < 3; ++i) {
            int f4i = t + i * 256;     // 0..767
            int row = f4i / 12, c4 = f4i % 12;
            float4 v = *reinterpret_cast<const float4*>(g + (size_t)(m0 + row) * 192 + k0 + c4 * 4);
            int c = c4 * 4;
            la[(c + 0) * 68 + row] = v.x; la[(c + 1) * 68 + row] = v.y;
            la[(c + 2) * 68 + row] = v.z; la[(c + 3) * 68 + row] = v.w;
        }
        #pragma unroll
        for (int i = 0; i < 18; ++i) {
            int idx = t + i * 256;     // 0..4607
            int c = idx / 48, k = idx % 48;
            lw[k * 97 + c] = W[(size_t)c * 192 + k0 + k];
        }
        __syncthreads();
        for (int k = 0; k < 48; ++k) {
            float4 a4 = *reinterpret_cast<const float4*>(&la[k * 68 + tr * 4]);
            float av0 = a4.x, av1 = a4.y, av2 = a4.z, av3 = a4.w;
            #pragma unroll
            for (int j = 0; j < 6; ++j) {
                float wv = lw[k * 97 + tc * 6 + j];
                acc[0][j] += av0 * wv; acc[1][j] += av1 * wv;
                acc[2][j] += av2 * wv; acc[3][j] += av3 * wv;
            }
        }
    }
    #pragma unroll
    for (int q = 0; q < 4; ++q) {
        int m = m0 + tr * 4 + q;
        #pragma unroll
        for (int j = 0; j < 6; ++j) {
            int c = tc * 6 + j;
            out[(size_t)m * 96 + c] = acc[q][j] + x[(size_t)m * 96 + c];
        }
    }
}

// ---------------------------------------------------------------------------
extern "C" void kernel_launch(void* const* d_in, const int* in_sizes, int n_in,
                              void* d_out, int out_size, void* d_ws, size_t ws_size,
                              hipStream_t stream)
{
    const float* x            = (const float*)d_in[0];
    const float* hbl          = (const float*)d_in[1];
    const float* ln_g         = (const float*)d_in[2];
    const float* ln_b         = (const float*)d_in[3];
    const float* in_proj_w    = (const float*)d_in[4];
    const float* in_proj_low_w= (const float*)d_in[5];
    const float* conv2d_w     = (const float*)d_in[6];
    const float* conv2d_b     = (const float*)d_in[7];
    const float* x_proj_w     = (const float*)d_in[8];
    const float* x_proj_w_low = (const float*)d_in[9];
    const float* conv_dt_w    = (const float*)d_in[10];
    const float* conv_B_w     = (const float*)d_in[11];
    const float* conv_C_w     = (const float*)d_in[12];
    const float* sgb_w1       = (const float*)d_in[13];
    const float* sgb_w2       = (const float*)d_in[14];
    const float* sgc_w1       = (const float*)d_in[15];
    const float* sgc_w2       = (const float*)d_in[16];
    const float* dt_proj_w    = (const float*)d_in[17];
    const float* dt_proj_b    = (const float*)d_in[18];
    const float* A_logs       = (const float*)d_in[19];
    const float* Ds           = (const float*)d_in[20];
    const float* outn_g       = (const float*)d_in[21];
    const float* outn_b       = (const float*)d_in[22];
    const float* out_proj_w   = (const float*)d_in[23];
    float* out = (float*)d_out;
    float* ws  = (float*)d_ws;

    // workspace layout (floats)
    float* z       = ws;                       // 6,291,456
    float* xi_raw  = z + 6291456;              // reused as hend after conv3x3
    float* xs      = xi_raw + 6291456;         // reused as gated
    float* low     = xs + 6291456;             // reused as y
    float* bs_low  = low + 6291456;            // 524,288
    float* cs_low  = bs_low + 524288;
    float* dts_raw = cs_low + 524288;          // 196,608
    float* bs_sum  = dts_raw + 196608;
    float* cs_sum  = bs_sum + 524288;
    float* dts_c   = cs_sum + 524288;          // 196,608
    float* bs_c    = dts_c + 196608;           // (B,L,16)
    float* cs_c    = bs_c + 524288;
    float* S_buf   = cs_c + 524288;            // 196,608 (tasks)
    float* hend_sg = S_buf + 196608;           // 196,608
    float* sumS_sg = hend_sg + 196608;         // 12,288
    float* hsg_in  = sumS_sg + 12288;          // 196,608
    float* hend    = xi_raw;                   // 3,145,728 (reuse)
    float* y       = low;
    float* gated   = xs;

    // 1) LN + in_proj (xi channel-major, z pos-major)
    gemm96_k<0><<<dim3(512, 6), 256, 0, stream>>>(x, in_proj_w, xi_raw, z, ln_g, ln_b);
    // 2) in_proj_low
    gemm96_k<1><<<dim3(512, 3), 256, 0, stream>>>(hbl, in_proj_low_w, low, nullptr, nullptr, nullptr);
    // 3) depthwise 3x3 + SiLU
    conv3x3_k<<<dim3(128, 192, 2), 128, 0, stream>>>(xi_raw, conv2d_w, conv2d_b, xs);
    // 4) low_dbl + SimpleGates
    lowdbl_gates_k<<<128, 256, 0, stream>>>(low, x_proj_w_low, sgb_w1, sgb_w2, sgc_w1, sgc_w2,
                                            bs_low, cs_low);
    // 5) x_dbl + sums
    xdbl_k<<<128, 256, 0, stream>>>(xs, x_proj_w, bs_low, cs_low, dts_raw, bs_sum, cs_sum);
    // 6) 1-D dilated depthwise convs
    conv1d_k<6, 0><<<768, 256, 0, stream>>>(dts_raw, conv_dt_w, dts_c);
    conv1d_k<16, 1><<<2048, 256, 0, stream>>>(bs_sum, conv_B_w, bs_c);
    conv1d_k<16, 1><<<2048, 256, 0, stream>>>(cs_sum, conv_C_w, cs_c);
    // 7) chunked selective scan (dt_proj+softplus fused into p1/p3)
    scan_p1_k<<<768, 256, 0, stream>>>(dts_c, dt_proj_w, dt_proj_b, xs, bs_c, A_logs, S_buf, hend);
    scan_p2a_k<<<768, 256, 0, stream>>>(A_logs, S_buf, hend, hend_sg, sumS_sg);
    scan_p2b_k<<<24, 256, 0, stream>>>(A_logs, sumS_sg, hend_sg, hsg_in);
    scan_p3_k<<<768, 256, 0, stream>>>(dts_c, dt_proj_w, dt_proj_b, xs, bs_c, cs_c,
                                       S_buf, hend, hsg_in, A_logs, Ds, y);
    // 8) out-LN + silu(z) gate (gated reuses xs)
    outln_k<<<1024, 256, 0, stream>>>(y, z, outn_g, outn_b, gated);
    // 9) out_proj + residual
    outproj_k<<<512, 256, 0, stream>>>(gated, out_proj_w, x, out);
}

// Round 4
// 451.586 us; speedup vs baseline: 1.3878x; 1.3878x over previous
//
#include <hip/hip_runtime.h>
#include <hip/hip_bf16.h>
#include <math.h>

// Problem constants
#define Bb 2
#define Hh 128
#define Wd 128
#define Cc 96
#define Dd 192
#define Ll 16384        // Hh*Wd
#define Nn 16
#define Rr 6
#define DL 3145728      // Dd*Ll
#define NCHUNK 512
#define CLEN 32
#define CSHIFT 9        // log2(NCHUNK)
#define NSG 32          // supergroups per chain (16 chunks each)

// scan layout: position l = c*32+tt  <->  p = tt*512 + c

__device__ __forceinline__ float siluf(float v) { return v / (1.f + __expf(-v)); }
__device__ __forceinline__ float geluf(float v) { return 0.5f * v * (1.f + erff(v * 0.70710678118654752f)); }
__device__ __forceinline__ float softplusf(float v) {
    float a = fabsf(v);
    return fmaxf(v, 0.f) + log1pf(__expf(-a));
}

// ---------------------------------------------------------------------------
// K2: GEMM with K=96.  A (M x 96) pos-major, W (Nout x 96) row-major.
// MODE 0: A = x, LN fused; o<192 -> xi (B,D,L), o>=192 -> z pos-major.
// MODE 1: A = high_branch_low (no LN); all outputs -> (B,D,L).
// ---------------------------------------------------------------------------
template <int MODE>
__global__ __launch_bounds__(256) void gemm96_k(
    const float* __restrict__ A, const float* __restrict__ W,
    float* __restrict__ outA, float* __restrict__ outB,
    const float* __restrict__ lng, const float* __restrict__ lnb)
{
    __shared__ float sA[96 * 68];   // [k][row], padded row stride 68
    __shared__ float sW[96 * 68];
    __shared__ float redS[512];
    __shared__ float meanS[64], rstdS[64];

    const int t = threadIdx.x;
    const int m0 = blockIdx.x * 64;
    const int n0 = blockIdx.y * 64;

    #pragma unroll
    for (int i = 0; i < 6; ++i) {
        int idx = t + i * 256;          // float4 index, 0..1535
        int row = idx / 24, c4 = idx % 24;
        float4 v = *reinterpret_cast<const float4*>(A + (size_t)(m0 + row) * 96 + c4 * 4);
        int c = c4 * 4;
        sA[(c + 0) * 68 + row] = v.x; sA[(c + 1) * 68 + row] = v.y;
        sA[(c + 2) * 68 + row] = v.z; sA[(c + 3) * 68 + row] = v.w;
    }
    #pragma unroll
    for (int i = 0; i < 6; ++i) {
        int idx = t + i * 256;
        int row = idx / 24, c4 = idx % 24;
        float4 v = *reinterpret_cast<const float4*>(W + (size_t)(n0 + row) * 96 + c4 * 4);
        int c = c4 * 4;
        sW[(c + 0) * 68 + row] = v.x; sW[(c + 1) * 68 + row] = v.y;
        sW[(c + 2) * 68 + row] = v.z; sW[(c + 3) * 68 + row] = v.w;
    }
    __syncthreads();

    if (MODE == 0) {
        int r = t & 63, part = t >> 6;          // 4 parts x 24 channels
        float s = 0.f, s2 = 0.f;
        for (int k = part * 24; k < part * 24 + 24; ++k) {
            float v = sA[k * 68 + r]; s += v; s2 += v * v;
        }
        redS[part * 64 + r] = s; redS[256 + part * 64 + r] = s2;
        __syncthreads();
        if (t < 64) {
            float ts = 0.f, ts2 = 0.f;
            #pragma unroll
            for (int p = 0; p < 4; ++p) { ts += redS[p * 64 + t]; ts2 += redS[256 + p * 64 + t]; }
            float mean = ts * (1.f / 96.f);
            float var = ts2 * (1.f / 96.f) - mean * mean;
            meanS[t] = mean; rstdS[t] = rsqrtf(var + 1e-5f);
        }
        __syncthreads();
        for (int k = part * 24; k < part * 24 + 24; ++k) {
            float v = sA[k * 68 + r];
            sA[k * 68 + r] = (v - meanS[r]) * rstdS[r] * lng[k] + lnb[k];
        }
        __syncthreads();
    }

    const int tc = t & 15, tr = t >> 4;
    float acc[4][4];
    #pragma unroll
    for (int q = 0; q < 4; ++q)
        #pragma unroll
        for (int j = 0; j < 4; ++j) acc[q][j] = 0.f;

    #pragma unroll 4
    for (int k = 0; k < 96; ++k) {
        float4 a4 = *reinterpret_cast<const float4*>(&sA[k * 68 + tr * 4]);
        float4 w4 = *reinterpret_cast<const float4*>(&sW[k * 68 + tc * 4]);
        acc[0][0] += a4.x * w4.x; acc[0][1] += a4.x * w4.y; acc[0][2] += a4.x * w4.z; acc[0][3] += a4.x * w4.w;
        acc[1][0] += a4.y * w4.x; acc[1][1] += a4.y * w4.y; acc[1][2] += a4.y * w4.z; acc[1][3] += a4.y * w4.w;
        acc[2][0] += a4.z * w4.x; acc[2][1] += a4.z * w4.y; acc[2][2] += a4.z * w4.z; acc[2][3] += a4.z * w4.w;
        acc[3][0] += a4.w * w4.x; acc[3][1] += a4.w * w4.y; acc[3][2] += a4.w * w4.z; acc[3][3] += a4.w * w4.w;
    }

    #pragma unroll
    for (int q = 0; q < 4; ++q) {
        int m = m0 + tr * 4 + q;
        int b = m >> 14, l = m & 16383;
        #pragma unroll
        for (int j = 0; j < 4; ++j) {
            int o = n0 + tc * 4 + j;
            float v = acc[q][j];
            if (MODE == 0) {
                if (o < Dd) outA[(size_t)b * DL + (size_t)o * Ll + l] = v;
                else        outB[(size_t)m * Dd + (o - Dd)] = v;
            } else {
                outA[(size_t)b * DL + (size_t)o * Ll + l] = v;
            }
        }
    }
}

// ---------------------------------------------------------------------------
// K3: tiled depthwise 3x3 conv + bias + SiLU.  Writes xs normal AND xs_scan.
// Block: one (b,d), 8 h-rows.  LDS-staged scan-layout writeout.
// ---------------------------------------------------------------------------
__global__ __launch_bounds__(256) void conv3x3_k(
    const float* __restrict__ xin, const float* __restrict__ cw,
    const float* __restrict__ cb, float* __restrict__ xs_n,
    float* __restrict__ xs_s)
{
    __shared__ float sx[10 * 128];
    __shared__ float sy[32 * 33];
    int t = threadIdx.x;
    int h0 = blockIdx.x * 8;
    int d = blockIdx.y;
    int b = blockIdx.z;
    size_t bd = (size_t)(b * Dd + d);
    const float* base = xin + bd * Ll;

    #pragma unroll
    for (int i = 0; i < 5; ++i) {
        int idx = t + i * 256;          // 0..1279
        int row = idx >> 7, col = idx & 127;
        int h = h0 - 1 + row;
        sx[idx] = (h >= 0 && h < Hh) ? base[h * Wd + col] : 0.f;
    }
    float wgt[9];
    #pragma unroll
    for (int i = 0; i < 9; ++i) wgt[i] = cw[d * 9 + i];
    float bias = cb[d];
    __syncthreads();

    #pragma unroll
    for (int j = 0; j < 4; ++j) {
        int oi = t + j * 256;           // 0..1023
        int oh = oi >> 7, ow = oi & 127;
        float acc = bias;
        #pragma unroll
        for (int ky = 0; ky < 3; ++ky) {
            const float* rp = &sx[(oh + ky) * 128];
            if (ow > 0)   acc += wgt[ky * 3 + 0] * rp[ow - 1];
                          acc += wgt[ky * 3 + 1] * rp[ow];
            if (ow < 127) acc += wgt[ky * 3 + 2] * rp[ow + 1];
        }
        float v = siluf(acc);
        xs_n[bd * Ll + (h0 + oh) * Wd + ow] = v;
        sy[(oh * 4 + (ow >> 5)) * 33 + (ow & 31)] = v;
    }
    __syncthreads();
    #pragma unroll
    for (int j = 0; j < 4; ++j) {
        int idx = t + j * 256;          // 0..1023
        int cc = idx & 31, tt = idx >> 5;
        xs_s[bd * Ll + tt * NCHUNK + h0 * 4 + cc] = sy[cc * 33 + tt];
    }
}

// ---------------------------------------------------------------------------
// K4a: low_dbl rows 6..37 + SimpleGate for B and C.  One thread per position.
// ---------------------------------------------------------------------------
__global__ __launch_bounds__(256) void lowdbl_gates_k(
    const float* __restrict__ low, const float* __restrict__ wl,
    const float* __restrict__ b1, const float* __restrict__ b2,
    const float* __restrict__ c1, const float* __restrict__ c2,
    float* __restrict__ bs_low, float* __restrict__ cs_low)
{
    __shared__ float wt[192 * 32];    // wt[d*32+c] = wl[(6+c)*192+d]
    __shared__ float w1b[192 * 16];
    __shared__ float w2bt[96 * 16];   // w2bt[j*16+c] = b2[c*96+j]
    __shared__ float w1c[192 * 16];
    __shared__ float w2ct[96 * 16];
    int t = threadIdx.x;
    for (int i = t; i < 32 * 192; i += 256) {
        int r = i / 192, dcol = i % 192;
        wt[dcol * 32 + r] = wl[(6 + r) * 192 + dcol];
    }
    for (int i = t; i < 3072; i += 256) { w1b[i] = b1[i]; w1c[i] = c1[i]; }
    for (int i = t; i < 1536; i += 256) {
        int c = i / 96, j = i % 96;
        w2bt[j * 16 + c] = b2[i]; w2ct[j * 16 + c] = c2[i];
    }
    __syncthreads();

    int pos = blockIdx.x * 256 + t;
    int b = pos >> 14, l = pos & 16383;
    const float* lp = low + (size_t)b * DL + l;

    float Bin[16], Cin[16];
    #pragma unroll
    for (int q = 0; q < 16; ++q) { Bin[q] = 0.f; Cin[q] = 0.f; }
    for (int d = 0; d < 192; ++d) {
        float v = lp[(size_t)d * Ll];
        const float4* w4p = reinterpret_cast<const float4*>(&wt[d * 32]);
        #pragma unroll
        for (int q = 0; q < 4; ++q) {
            float4 f = w4p[q];
            Bin[4 * q + 0] += v * f.x; Bin[4 * q + 1] += v * f.y;
            Bin[4 * q + 2] += v * f.z; Bin[4 * q + 3] += v * f.w;
        }
        #pragma unroll
        for (int q = 0; q < 4; ++q) {
            float4 f = w4p[4 + q];
            Cin[4 * q + 0] += v * f.x; Cin[4 * q + 1] += v * f.y;
            Cin[4 * q + 2] += v * f.z; Cin[4 * q + 3] += v * f.w;
        }
    }

    float Bout[16], Cout[16];
    #pragma unroll
    for (int q = 0; q < 16; ++q) { Bout[q] = 0.f; Cout[q] = 0.f; }
    for (int j = 0; j < 96; ++j) {
        float h1 = 0.f, h2 = 0.f, g1 = 0.f, g2 = 0.f;
        #pragma unroll
        for (int q = 0; q < 4; ++q) {
            float4 a = reinterpret_cast<const float4*>(&w1b[j * 16])[q];
            float4 cvec = reinterpret_cast<const float4*>(&w1b[(j + 96) * 16])[q];
            h1 += a.x * Bin[4 * q] + a.y * Bin[4 * q + 1] + a.z * Bin[4 * q + 2] + a.w * Bin[4 * q + 3];
            h2 += cvec.x * Bin[4 * q] + cvec.y * Bin[4 * q + 1] + cvec.z * Bin[4 * q + 2] + cvec.w * Bin[4 * q + 3];
            float4 ac = reinterpret_cast<const float4*>(&w1c[j * 16])[q];
            float4 cc = reinterpret_cast<const float4*>(&w1c[(j + 96) * 16])[q];
            g1 += ac.x * Cin[4 * q] + ac.y * Cin[4 * q + 1] + ac.z * Cin[4 * q + 2] + ac.w * Cin[4 * q + 3];
            g2 += cc.x * Cin[4 * q] + cc.y * Cin[4 * q + 1] + cc.z * Cin[4 * q + 2] + cc.w * Cin[4 * q + 3];
        }
        float gB = geluf(h1) * h2;
        float gC = geluf(g1) * g2;
        #pragma unroll
        for (int q = 0; q < 4; ++q) {
            float4 f = reinterpret_cast<const float4*>(&w2bt[j * 16])[q];
            Bout[4 * q + 0] += f.x * gB; Bout[4 * q + 1] += f.y * gB;
            Bout[4 * q + 2] += f.z * gB; Bout[4 * q + 3] += f.w * gB;
            float4 fc = reinterpret_cast<const float4*>(&w2ct[j * 16])[q];
            Cout[4 * q + 0] += fc.x * gC; Cout[4 * q + 1] += fc.y * gC;
            Cout[4 * q + 2] += fc.z * gC; Cout[4 * q + 3] += fc.w * gC;
        }
    }
    #pragma unroll
    for (int c = 0; c < 16; ++c) {
        bs_low[(size_t)b * 16 * Ll + (size_t)c * Ll + l] = Bout[c];
        cs_low[(size_t)b * 16 * Ll + (size_t)c * Ll + l] = Cout[c];
    }
}

// ---------------------------------------------------------------------------
// K4b: x_dbl (rows 0..37), writes dts_raw and Bs+Bs_low / Cs+Cs_low (normal).
// ---------------------------------------------------------------------------
__global__ __launch_bounds__(256) void xdbl_k(
    const float* __restrict__ xs, const float* __restrict__ xw,
    const float* __restrict__ bs_low, const float* __restrict__ cs_low,
    float* __restrict__ dts_raw, float* __restrict__ bs_sum, float* __restrict__ cs_sum)
{
    __shared__ float wdt[192 * 6];
    __shared__ float wB[192 * 16];
    __shared__ float wC[192 * 16];
    int t = threadIdx.x;
    for (int i = t; i < 38 * 192; i += 256) {
        int r = i / 192, dcol = i % 192;
        float v = xw[i];
        if (r < 6)       wdt[dcol * 6 + r] = v;
        else if (r < 22) wB[dcol * 16 + (r - 6)] = v;
        else             wC[dcol * 16 + (r - 22)] = v;
    }
    __syncthreads();

    int pos = blockIdx.x * 256 + t;
    int b = pos >> 14, l = pos & 16383;
    const float* xp = xs + (size_t)b * DL + l;

    float da[6], Ba[16], Ca[16];
    #pragma unroll
    for (int q = 0; q < 6; ++q) da[q] = 0.f;
    #pragma unroll
    for (int q = 0; q < 16; ++q) { Ba[q] = 0.f; Ca[q] = 0.f; }

    for (int d = 0; d < 192; ++d) {
        float v = xp[(size_t)d * Ll];
        #pragma unroll
        for (int q = 0; q < 3; ++q) {
            float2 f = reinterpret_cast<const float2*>(&wdt[d * 6])[q];
            da[2 * q] += v * f.x; da[2 * q + 1] += v * f.y;
        }
        #pragma unroll
        for (int q = 0; q < 4; ++q) {
            float4 f = reinterpret_cast<const float4*>(&wB[d * 16])[q];
            Ba[4 * q + 0] += v * f.x; Ba[4 * q + 1] += v * f.y;
            Ba[4 * q + 2] += v * f.z; Ba[4 * q + 3] += v * f.w;
        }
        #pragma unroll
        for (int q = 0; q < 4; ++q) {
            float4 f = reinterpret_cast<const float4*>(&wC[d * 16])[q];
            Ca[4 * q + 0] += v * f.x; Ca[4 * q + 1] += v * f.y;
            Ca[4 * q + 2] += v * f.z; Ca[4 * q + 3] += v * f.w;
        }
    }
    #pragma unroll
    for (int r = 0; r < 6; ++r)
        dts_raw[(size_t)b * 6 * Ll + (size_t)r * Ll + l] = da[r];
    #pragma unroll
    for (int c = 0; c < 16; ++c) {
        size_t o = (size_t)b * 16 * Ll + (size_t)c * Ll + l;
        bs_sum[o] = Ba[c] + bs_low[o];
        cs_sum[o] = Ca[c] + cs_low[o];
    }
}

// ---------------------------------------------------------------------------
// K5a: dt depthwise conv (6 ch), k=7 dil=2 pad=6, LDS transpose -> scan layout
// dts_scan[(b*6+r)*Ll + tt*512 + c].  Tile: 16 chunks (512 l).
// ---------------------------------------------------------------------------
__global__ __launch_bounds__(256) void conv1d_dt_k(
    const float* __restrict__ in, const float* __restrict__ w,
    float* __restrict__ out)
{
    __shared__ float si[6 * 524];
    __shared__ float so[6 * 528];     // [r][cc][tt], cc stride 33
    int t = threadIdx.x;
    int ct = blockIdx.x;              // 0..31
    int b = blockIdx.y;
    int c0 = ct * 16, l0 = ct * 512;

    for (int i = 0; i < 13; ++i) {
        int idx = t + i * 256;
        if (idx < 3144) {
            int r = idx / 524, ii = idx % 524;
            int l = l0 - 6 + ii;
            si[idx] = (l >= 0 && l < Ll) ? in[(size_t)(b * 6 + r) * Ll + l] : 0.f;
        }
    }
    __syncthreads();
    #pragma unroll
    for (int i = 0; i < 12; ++i) {
        int idx = t + i * 256;        // 0..3071
        int r = idx >> 9, pos = idx & 511;
        const float* sp = &si[r * 524 + pos];
        float acc = 0.f;
        #pragma unroll
        for (int k = 0; k < 7; ++k) acc += w[r * 7 + k] * sp[2 * k];
        so[r * 528 + (pos >> 5) * 33 + (pos & 31)] = acc;
    }
    __syncthreads();
    #pragma unroll
    for (int i = 0; i < 12; ++i) {
        int idx = t + i * 256;
        int r = idx >> 9, rem = idx & 511;
        int tt = rem >> 4, cc = rem & 15;
        out[(size_t)(b * 6 + r) * Ll + tt * NCHUNK + c0 + cc] = so[r * 528 + cc * 33 + tt];
    }
}

// ---------------------------------------------------------------------------
// K5b: B/C depthwise conv (16 ch), LDS transpose -> scan layout
// out[((b*Ll) + tt*512 + c)*16 + ch].  Tile: 8 chunks (256 l).
// ---------------------------------------------------------------------------
__global__ __launch_bounds__(256) void conv1d_bc_k(
    const float* __restrict__ in, const float* __restrict__ w,
    float* __restrict__ out)
{
    __shared__ float si[16 * 268];
    __shared__ float so[256 * 17];    // [pos][ch] pad 17
    int t = threadIdx.x;
    int ct = blockIdx.x;              // 0..63
    int b = blockIdx.y;
    int c0 = ct * 8, l0 = ct * 256;

    for (int i = 0; i < 17; ++i) {
        int idx = t + i * 256;
        if (idx < 4288) {
            int ch = idx / 268, ii = idx % 268;
            int l = l0 - 6 + ii;
            si[idx] = (l >= 0 && l < Ll) ? in[(size_t)(b * 16 + ch) * Ll + l] : 0.f;
        }
    }
    __syncthreads();
    #pragma unroll
    for (int i = 0; i < 16; ++i) {
        int idx = t + i * 256;        // 0..4095
        int ch = idx >> 8, pos = idx & 255;
        const float* sp = &si[ch * 268 + pos];
        float acc = 0.f;
        #pragma unroll
        for (int k = 0; k < 7; ++k) acc += w[ch * 7 + k] * sp[2 * k];
        so[pos * 17 + ch] = acc;
    }
    __syncthreads();
    #pragma unroll
    for (int i = 0; i < 16; ++i) {
        int idx = t + i * 256;        // 0..4095
        int ch = idx & 15, cc = (idx >> 4) & 7, tt = idx >> 7;
        out[((size_t)b * Ll + tt * NCHUNK + c0 + cc) * 16 + ch] = so[(cc * 32 + tt) * 17 + ch];
    }
}

// ---------------------------------------------------------------------------
// K7: chunked selective scan in scan layout.  Thread = (bd, c); 16 states/thread.
// ---------------------------------------------------------------------------
__global__ __launch_bounds__(256) void scan_p1_k(
    const float* __restrict__ dts_s, const float* __restrict__ dw,
    const float* __restrict__ dpb_, const float* __restrict__ xs_s,
    const float* __restrict__ bs_s, const float* __restrict__ A_logs,
    float* __restrict__ S_buf, float* __restrict__ hend)
{
    int task = blockIdx.x * 256 + threadIdx.x;   // 196608
    int c = task & (NCHUNK - 1);
    int bd = task >> CSHIFT;
    int d = bd % Dd, b = bd / Dd;

    float Av[16];
    #pragma unroll
    for (int n = 0; n < 16; ++n) Av[n] = -__expf(A_logs[d * 16 + n]);
    float dwv[6];
    #pragma unroll
    for (int r = 0; r < 6; ++r) dwv[r] = dw[d * 6 + r];
    float dpb = dpb_[d];

    const float* up = xs_s + (size_t)bd * Ll + c;
    const float* tp = dts_s + (size_t)b * 6 * Ll + c;
    const float* bp = bs_s + ((size_t)b * Ll + c) * 16;

    float h[16];
    #pragma unroll
    for (int n = 0; n < 16; ++n) h[n] = 0.f;
    float S = 0.f;

    for (int tt = 0; tt < CLEN; ++tt) {
        float u = up[tt * NCHUNK];
        float acc = dpb;
        #pragma unroll
        for (int r = 0; r < 6; ++r) acc += dwv[r] * tp[(size_t)r * Ll + tt * NCHUNK];
        float dlt = softplusf(acc);
        S += dlt;
        float du = dlt * u;
        const float4* brow = reinterpret_cast<const float4*>(bp + (size_t)tt * NCHUNK * 16);
        float4 B0 = brow[0], B1 = brow[1], B2 = brow[2], B3 = brow[3];
        float Bv[16] = {B0.x, B0.y, B0.z, B0.w, B1.x, B1.y, B1.z, B1.w,
                        B2.x, B2.y, B2.z, B2.w, B3.x, B3.y, B3.z, B3.w};
        #pragma unroll
        for (int n = 0; n < 16; ++n)
            h[n] = __expf(dlt * Av[n]) * h[n] + du * Bv[n];
    }
    float4* hp = reinterpret_cast<float4*>(hend + (size_t)task * 16);
    hp[0] = make_float4(h[0], h[1], h[2], h[3]);
    hp[1] = make_float4(h[4], h[5], h[6], h[7]);
    hp[2] = make_float4(h[8], h[9], h[10], h[11]);
    hp[3] = make_float4(h[12], h[13], h[14], h[15]);
    S_buf[task] = S;
}

// p2a: per (bd, sg, n) serial over the 16 chunks of a supergroup (in place).
__global__ __launch_bounds__(256) void scan_p2a_k(
    const float* __restrict__ A_logs, float* __restrict__ S_buf,
    float* __restrict__ hend, float* __restrict__ hend_sg,
    float* __restrict__ sumS_sg)
{
    int tid = blockIdx.x * 256 + threadIdx.x;   // 196608
    int n = tid & 15;
    int sg = (tid >> 4) & (NSG - 1);
    int bd = tid >> CSHIFT;
    int d = bd % Dd;
    float An = -__expf(A_logs[d * 16 + n]);
    float h = 0.f, prefS = 0.f;
    int task0 = bd * NCHUNK + sg * 16;
    for (int c = 0; c < 16; ++c) {
        int task = task0 + c;
        float Sv = S_buf[task];
        float he = hend[(size_t)task * 16 + n];
        hend[(size_t)task * 16 + n] = h;        // local hin
        if (n == 0) S_buf[task] = prefS;        // local prefix-S
        h = __expf(An * Sv) * h + he;
        prefS += Sv;
    }
    int idx = bd * NSG + sg;
    hend_sg[(size_t)idx * 16 + n] = h;
    if (n == 0) sumS_sg[idx] = prefS;
}

// p2b: per (bd, n) serial over the 32 supergroups.
__global__ __launch_bounds__(256) void scan_p2b_k(
    const float* __restrict__ A_logs, const float* __restrict__ sumS_sg,
    const float* __restrict__ hend_sg, float* __restrict__ hsg_in)
{
    int tid = blockIdx.x * 256 + threadIdx.x;   // 6144
    int n = tid & 15;
    int bd = tid >> 4;
    if (bd >= Bb * Dd) return;
    int d = bd % Dd;
    float An = -__expf(A_logs[d * 16 + n]);
    float h = 0.f;
    for (int sg = 0; sg < NSG; ++sg) {
        int idx = bd * NSG + sg;
        hsg_in[(size_t)idx * 16 + n] = h;
        h = __expf(An * sumS_sg[idx]) * h + hend_sg[(size_t)idx * 16 + n];
    }
}

// p3: recompute with carry; writes y in scan layout.
// NOTE: xs_s and y_s intentionally ALIAS (in-place u -> y); no __restrict__
// on those two.  Each address is read (u) before being written (y) by the
// same thread in the same iteration, and threads touch disjoint addresses.
__global__ __launch_bounds__(256) void scan_p3_k(
    const float* __restrict__ dts_s, const float* __restrict__ dw,
    const float* __restrict__ dpb_, const float* xs_s,
    const float* __restrict__ bs_s, const float* __restrict__ cs_s,
    const float* __restrict__ S_buf, const float* __restrict__ hend,
    const float* __restrict__ hsg_in, const float* __restrict__ A_logs,
    const float* __restrict__ Ds, float* y_s)
{
    int task = blockIdx.x * 256 + threadIdx.x;
    int c = task & (NCHUNK - 1);
    int bd = task >> CSHIFT;
    int d = bd % Dd, b = bd / Dd;
    int sg = c >> 4;

    float Av[16];
    #pragma unroll
    for (int n = 0; n < 16; ++n) Av[n] = -__expf(A_logs[d * 16 + n]);
    float dwv[6];
    #pragma unroll
    for (int r = 0; r < 6; ++r) dwv[r] = dw[d * 6 + r];
    float dpb = dpb_[d];
    float Dsd = Ds[d];

    float prefS = S_buf[task];
    const float* hsgp = hsg_in + ((size_t)(bd * NSG + sg)) * 16;
    const float* hlp = hend + (size_t)task * 16;
    float h[16];
    #pragma unroll
    for (int n = 0; n < 16; ++n)
        h[n] = __expf(Av[n] * prefS) * hsgp[n] + hlp[n];

    const float* up = xs_s + (size_t)bd * Ll + c;
    const float* tp = dts_s + (size_t)b * 6 * Ll + c;
    const float* bp = bs_s + ((size_t)b * Ll + c) * 16;
    const float* cp = cs_s + ((size_t)b * Ll + c) * 16;
    float* yp = y_s + (size_t)bd * Ll + c;

    for (int tt = 0; tt < CLEN; ++tt) {
        float u = up[tt * NCHUNK];
        float acc = dpb;
        #pragma unroll
        for (int r = 0; r < 6; ++r) acc += dwv[r] * tp[(size_t)r * Ll + tt * NCHUNK];
        float dlt = softplusf(acc);
        float du = dlt * u;
        const float4* brow = reinterpret_cast<const float4*>(bp + (size_t)tt * NCHUNK * 16);
        float4 B0 = brow[0], B1 = brow[1], B2 = brow[2], B3 = brow[3];
        float Bv[16] = {B0.x, B0.y, B0.z, B0.w, B1.x, B1.y, B1.z, B1.w,
                        B2.x, B2.y, B2.z, B2.w, B3.x, B3.y, B3.z, B3.w};
        const float4* crow = reinterpret_cast<const float4*>(cp + (size_t)tt * NCHUNK * 16);
        float4 C0 = crow[0], C1 = crow[1], C2 = crow[2], C3 = crow[3];
        float Cv[16] = {C0.x, C0.y, C0.z, C0.w, C1.x, C1.y, C1.z, C1.w,
                        C2.x, C2.y, C2.z, C2.w, C3.x, C3.y, C3.z, C3.w};
        float yv = Dsd * u;
        #pragma unroll
        for (int n = 0; n < 16; ++n) {
            h[n] = __expf(dlt * Av[n]) * h[n] + du * Bv[n];
            yv += h[n] * Cv[n];
        }
        yp[tt * NCHUNK] = yv;
    }
}

// ---------------------------------------------------------------------------
// K8: out-LayerNorm over D=192 + silu(z) gating.  Tile = 64 consecutive p.
// Reads y_scan coalesced; z/gated pos-major rows.
// ---------------------------------------------------------------------------
__global__ __launch_bounds__(256) void outln_k(
    const float* __restrict__ y_s, const float* __restrict__ z,
    const float* __restrict__ og, const float* __restrict__ ob,
    float* __restrict__ gated)
{
    __shared__ float ly[192 * 68];
    __shared__ float redS[512];
    __shared__ float meanS[64], rstdS[64];
    __shared__ float sog[192], sob[192];
    int t = threadIdx.x;
    int tile = blockIdx.x;            // 0..511
    int b = tile >> 8;
    int p0 = (tile & 255) * 64;
    const float* yb = y_s + (size_t)b * DL + p0;

    #pragma unroll
    for (int i = 0; i < 12; ++i) {
        int f4 = t + i * 256;         // 0..3071
        int dch = f4 >> 4, q = f4 & 15;
        float4 v = *reinterpret_cast<const float4*>(yb + (size_t)dch * Ll + q * 4);
        *reinterpret_cast<float4*>(&ly[dch * 68 + q * 4]) = v;
    }
    if (t < 192) { sog[t] = og[t]; sob[t] = ob[t]; }
    __syncthreads();

    int pp = t & 63, part = t >> 6;   // 4 parts x 48 channels
    float s = 0.f, s2 = 0.f;
    for (int dch = part * 48; dch < part * 48 + 48; ++dch) {
        float v = ly[dch * 68 + pp]; s += v; s2 += v * v;
    }
    redS[part * 64 + pp] = s; redS[256 + part * 64 + pp] = s2;
    __syncthreads();
    if (t < 64) {
        float ts = 0.f, ts2 = 0.f;
        #pragma unroll
        for (int q = 0; q < 4; ++q) { ts += redS[q * 64 + t]; ts2 += redS[256 + q * 64 + t]; }
        float mean = ts * (1.f / 192.f);
        float var = ts2 * (1.f / 192.f) - mean * mean;
        meanS[t] = mean; rstdS[t] = rsqrtf(var + 1e-5f);
    }
    __syncthreads();

    int pos = t >> 2, dgrp = t & 3;
    int p = p0 + pos;
    int l = ((p & (NCHUNK - 1)) << 5) + (p >> CSHIFT);
    size_t zrow = ((size_t)b * Ll + l) * Dd;
    float mean = meanS[pos], rstd = rstdS[pos];
    #pragma unroll
    for (int k = 0; k < 12; ++k) {
        int d0 = (dgrp + 4 * k) * 4;
        float4 zv = *reinterpret_cast<const float4*>(z + zrow + d0);
        float4 r;
        r.x = ((ly[(d0 + 0) * 68 + pos] - mean) * rstd * sog[d0 + 0] + sob[d0 + 0]) * siluf(zv.x);
        r.y = ((ly[(d0 + 1) * 68 + pos] - mean) * rstd * sog[d0 + 1] + sob[d0 + 1]) * siluf(zv.y);
        r.z = ((ly[(d0 + 2) * 68 + pos] - mean) * rstd * sog[d0 + 2] + sob[d0 + 2]) * siluf(zv.z);
        r.w = ((ly[(d0 + 3) * 68 + pos] - mean) * rstd * sog[d0 + 3] + sob[d0 + 3]) * siluf(zv.w);
        *reinterpret_cast<float4*>(gated + zrow + d0) = r;
    }
}

// ---------------------------------------------------------------------------
// K9: out_proj GEMM (M=32768, K=192, N=96) + residual x.
// ---------------------------------------------------------------------------
__global__ __launch_bounds__(256) void outproj_k(
    const float* __restrict__ g, const float* __restrict__ W,
    const float* __restrict__ x, float* __restrict__ out)
{
    __shared__ float la[48 * 68];     // [k][row]
    __shared__ float lw[48 * 97];     // [k][c] padded
    int t = threadIdx.x;
    int m0 = blockIdx.x * 64;
    int tc = t & 15, tr = t >> 4;
    float acc[4][6];
    #pragma unroll
    for (int q = 0; q < 4; ++q)
        #pragma unroll
        for (int j = 0; j < 6; ++j) acc[q][j] = 0.f;

    for (int k0 = 0; k0 < 192; k0 += 48) {
        __syncthreads();
        #pragma unroll
        for (int i = 0; i < 3; ++i) {
            int f4i = t + i * 256;     // 0..767
            int row = f4i / 12, c4 = f4i % 12;
            float4 v = *reinterpret_cast<const float4*>(g + (size_t)(m0 + row) * 192 + k0 + c4 * 4);
            int c = c4 * 4;
            la[(c + 0) * 68 + row] = v.x; la[(c + 1) * 68 + row] = v.y;
            la[(c + 2) * 68 + row] = v.z; la[(c + 3) * 68 + row] = v.w;
        }
        #pragma unroll
        for (int i = 0; i < 18; ++i) {
            int idx = t + i * 256;     // 0..4607
            int c = idx / 48, k = idx % 48;
            lw[k * 97 + c] = W[(size_t)c * 192 + k0 + k];
        }
        __syncthreads();
        for (int k = 0; k < 48; ++k) {
            float4 a4 = *reinterpret_cast<const float4*>(&la[k * 68 + tr * 4]);
            float av0 = a4.x, av1 = a4.y, av2 = a4.z, av3 = a4.w;
            #pragma unroll
            for (int j = 0; j < 6; ++j) {
                float wv = lw[k * 97 + tc * 6 + j];
                acc[0][j] += av0 * wv; acc[1][j] += av1 * wv;
                acc[2][j] += av2 * wv; acc[3][j] += av3 * wv;
            }
        }
    }
    #pragma unroll
    for (int q = 0; q < 4; ++q) {
        int m = m0 + tr * 4 + q;
        #pragma unroll
        for (int j = 0; j < 6; ++j) {
            int c = tc * 6 + j;
            out[(size_t)m * 96 + c] = acc[q][j] + x[(size_t)m * 96 + c];
        }
    }
}

// ---------------------------------------------------------------------------
extern "C" void kernel_launch(void* const* d_in, const int* in_sizes, int n_in,
                              void* d_out, int out_size, void* d_ws, size_t ws_size,
                              hipStream_t stream)
{
    const float* x            = (const float*)d_in[0];
    const float* hbl          = (const float*)d_in[1];
    const float* ln_g         = (const float*)d_in[2];
    const float* ln_b         = (const float*)d_in[3];
    const float* in_proj_w    = (const float*)d_in[4];
    const float* in_proj_low_w= (const float*)d_in[5];
    const float* conv2d_w     = (const float*)d_in[6];
    const float* conv2d_b     = (const float*)d_in[7];
    const float* x_proj_w     = (const float*)d_in[8];
    const float* x_proj_w_low = (const float*)d_in[9];
    const float* conv_dt_w    = (const float*)d_in[10];
    const float* conv_B_w     = (const float*)d_in[11];
    const float* conv_C_w     = (const float*)d_in[12];
    const float* sgb_w1       = (const float*)d_in[13];
    const float* sgb_w2       = (const float*)d_in[14];
    const float* sgc_w1       = (const float*)d_in[15];
    const float* sgc_w2       = (const float*)d_in[16];
    const float* dt_proj_w    = (const float*)d_in[17];
    const float* dt_proj_b    = (const float*)d_in[18];
    const float* A_logs       = (const float*)d_in[19];
    const float* Ds           = (const float*)d_in[20];
    const float* outn_g       = (const float*)d_in[21];
    const float* outn_b       = (const float*)d_in[22];
    const float* out_proj_w   = (const float*)d_in[23];
    float* out = (float*)d_out;
    float* ws  = (float*)d_ws;

    // workspace layout (floats) — total 28,258,304 floats = 113.0 MB
    float* z       = ws;                       // 6,291,456  (live to outln)
    float* xi_raw  = z + 6291456;              // 6,291,456  -> hend reuse
    float* xs      = xi_raw + 6291456;         // 6,291,456  -> gated reuse
    float* low     = xs + 6291456;             // 6,291,456  -> xs_scan / y_scan reuse
    float* bs_low  = low + 6291456;            // 524,288    -> bs_scan reuse
    float* cs_low  = bs_low + 524288;          // 524,288    -> cs_scan reuse
    float* dts_raw = cs_low + 524288;          // 196,608
    float* bs_sum  = dts_raw + 196608;         // 524,288
    float* cs_sum  = bs_sum + 524288;          // 524,288
    float* dts_scan= cs_sum + 524288;          // 196,608
    float* S_buf   = dts_scan + 196608;        // 196,608
    float* hend_sg = S_buf + 196608;           // 196,608
    float* sumS_sg = hend_sg + 196608;         // 12,288
    float* hsg_in  = sumS_sg + 12288;          // 196,608
    float* xs_scan = low;                      // reuse (low dead after lowdbl_gates)
    float* hend    = xi_raw;                   // reuse (xi dead after conv3x3)
    float* bs_scan = bs_low;                   // reuse (bs_low dead after xdbl)
    float* cs_scan = cs_low;
    float* y_scan  = xs_scan;                  // IN-PLACE over xs_scan in p3
    float* gated   = xs;                       // reuse (xs dead after xdbl)

    // 1) LN + in_proj (xi channel-major, z pos-major)
    gemm96_k<0><<<dim3(512, 6), 256, 0, stream>>>(x, in_proj_w, xi_raw, z, ln_g, ln_b);
    // 2) in_proj_low
    gemm96_k<1><<<dim3(512, 3), 256, 0, stream>>>(hbl, in_proj_low_w, low, nullptr, nullptr, nullptr);
    // 3) low_dbl + SimpleGates (BEFORE conv3x3 so `low` can be reused)
    lowdbl_gates_k<<<128, 256, 0, stream>>>(low, x_proj_w_low, sgb_w1, sgb_w2, sgc_w1, sgc_w2,
                                            bs_low, cs_low);
    // 4) depthwise 3x3 + SiLU (writes xs normal + xs_scan)
    conv3x3_k<<<dim3(16, 192, 2), 256, 0, stream>>>(xi_raw, conv2d_w, conv2d_b, xs, xs_scan);
    // 5) x_dbl + sums (normal layout)
    xdbl_k<<<128, 256, 0, stream>>>(xs, x_proj_w, bs_low, cs_low, dts_raw, bs_sum, cs_sum);
    // 6) 1-D dilated depthwise convs -> scan layouts
    conv1d_dt_k<<<dim3(32, 2), 256, 0, stream>>>(dts_raw, conv_dt_w, dts_scan);
    conv1d_bc_k<<<dim3(64, 2), 256, 0, stream>>>(bs_sum, conv_B_w, bs_scan);
    conv1d_bc_k<<<dim3(64, 2), 256, 0, stream>>>(cs_sum, conv_C_w, cs_scan);
    // 7) chunked selective scan (dt_proj+softplus fused)
    scan_p1_k<<<768, 256, 0, stream>>>(dts_scan, dt_proj_w, dt_proj_b, xs_scan, bs_scan,
                                       A_logs, S_buf, hend);
    scan_p2a_k<<<768, 256, 0, stream>>>(A_logs, S_buf, hend, hend_sg, sumS_sg);
    scan_p2b_k<<<24, 256, 0, stream>>>(A_logs, sumS_sg, hend_sg, hsg_in);
    scan_p3_k<<<768, 256, 0, stream>>>(dts_scan, dt_proj_w, dt_proj_b, xs_scan, bs_scan, cs_scan,
                                       S_buf, hend, hsg_in, A_logs, Ds, y_scan);
    // 8) out-LN + silu(z) gate (gated reuses xs)
    outln_k<<<512, 256, 0, stream>>>(y_scan, z, outn_g, outn_b, gated);
    // 9) out_proj + residual
    outproj_k<<<512, 256, 0, stream>>>(gated, out_proj_w, x, out);
}